// Round 1
// baseline (179.553 us; speedup 1.0000x reference)
//
#include <hip/hip_runtime.h>
#include <math.h>

#define NB   16
#define DIN  1024
#define TT   4096
#define DC   8
#define NK   1024
#define TILE 256
#define NTT  (TT/TILE)    // 16
#define DCH  256
#define NDC  (DIN/DCH)    // 4
#define OCH  128
#define NOC  (DIN/OCH)    // 8

// d_out offsets (floats), in reference return order
#define OFF_CL  ((size_t)NB*DIN*TT)          // 67108864
#define OFF_CB  (OFF_CL + NB)                // +16
#define OFF_IDX (OFF_CB + NB)                // +16
#define OFF_ZE  (OFF_IDX + (size_t)NB*TT)    // +65536

// ---------------- K1: in_proj partial sums (d-split x4) ----------------
__global__ __launch_bounds__(256) void vq_k1_inproj(const float* __restrict__ z,
    const float* __restrict__ in_w, float* __restrict__ P)
{
  __shared__ float wt[DCH*DC];
  const int tid = threadIdx.x;
  const int tt = blockIdx.x, b = blockIdx.y, dc = blockIdx.z;
  const int dbase = dc*DCH;
  #pragma unroll
  for (int o = 0; o < DC; ++o)
    wt[tid*DC + o] = in_w[o*DIN + dbase + tid];
  __syncthreads();
  const int t = tt*TILE + tid;
  const float* zp = z + ((size_t)b*DIN + dbase)*TT + t;
  float acc[DC];
  #pragma unroll
  for (int o = 0; o < DC; ++o) acc[o] = 0.f;
  #pragma unroll 8
  for (int d = 0; d < DCH; ++d) {
    const float v = zp[(size_t)d*TT];
    const float4 w0 = *(const float4*)&wt[d*DC];
    const float4 w1 = *(const float4*)&wt[d*DC+4];
    acc[0] = fmaf(v, w0.x, acc[0]);
    acc[1] = fmaf(v, w0.y, acc[1]);
    acc[2] = fmaf(v, w0.z, acc[2]);
    acc[3] = fmaf(v, w0.w, acc[3]);
    acc[4] = fmaf(v, w1.x, acc[4]);
    acc[5] = fmaf(v, w1.y, acc[5]);
    acc[6] = fmaf(v, w1.z, acc[6]);
    acc[7] = fmaf(v, w1.w, acc[7]);
  }
  float* pp = P + ((size_t)(dc*NB + b)*DC)*TT + t;
  #pragma unroll
  for (int o = 0; o < DC; ++o) pp[(size_t)o*TT] = acc[o];
}

// ---------------- K2: combine + VQ search + rotation trick ----------------
__global__ __launch_bounds__(256) void vq_k2_search(const float* __restrict__ P,
    const float* __restrict__ in_b, const float* __restrict__ cbk,
    float* __restrict__ dout, float* __restrict__ zq, float* __restrict__ lpart)
{
  __shared__ float cn[NK*DC];   // 32 KB normalized codebook
  __shared__ float cn2[NK];     // 4 KB sum(cn^2)
  __shared__ float lred[256];
  const int tid = threadIdx.x;
  const int tt = blockIdx.x, b = blockIdx.y;

  // stage + normalize codebook (replicates _normalize exactly: x / max(||x||,1e-12))
  for (int k = tid; k < NK; k += 256) {
    float c[DC];
    const float4 c0 = *(const float4*)&cbk[k*DC];
    const float4 c1 = *(const float4*)&cbk[k*DC+4];
    c[0]=c0.x; c[1]=c0.y; c[2]=c0.z; c[3]=c0.w;
    c[4]=c1.x; c[5]=c1.y; c[6]=c1.z; c[7]=c1.w;
    float ss = 0.f;
    #pragma unroll
    for (int i = 0; i < DC; ++i) ss = fmaf(c[i], c[i], ss);
    const float den = fmaxf(sqrtf(ss), 1e-12f);
    float s2 = 0.f;
    #pragma unroll
    for (int i = 0; i < DC; ++i) { const float v = c[i]/den; cn[k*DC+i] = v; s2 = fmaf(v, v, s2); }
    cn2[k] = s2;
  }
  __syncthreads();

  const int t = tt*TILE + tid;
  // e = z_e[b,:,t] = sum of 4 chunk partials + bias (chunk order = d order)
  float e[DC];
  {
    const float* pp = P + ((size_t)b*DC)*TT + t;
    const size_t cs = (size_t)NB*DC*TT;
    #pragma unroll
    for (int o = 0; o < DC; ++o) {
      float s = pp[(size_t)o*TT];
      s += pp[cs   + (size_t)o*TT];
      s += pp[2*cs + (size_t)o*TT];
      s += pp[3*cs + (size_t)o*TT];
      e[o] = s + in_b[o];
    }
  }
  #pragma unroll
  for (int o = 0; o < DC; ++o)
    dout[OFF_ZE + ((size_t)b*DC + o)*TT + t] = e[o];

  float se = 0.f;
  #pragma unroll
  for (int i = 0; i < DC; ++i) se = fmaf(e[i], e[i], se);
  const float ne = sqrtf(se);
  const float dene = fmaxf(ne, 1e-12f);
  float en[DC];
  #pragma unroll
  for (int i = 0; i < DC; ++i) en[i] = e[i]/dene;
  float en2 = 0.f;
  #pragma unroll
  for (int i = 0; i < DC; ++i) en2 = fmaf(en[i], en[i], en2);

  // argmin of dist = (en2 - 2*dot) + cn2[k]; strict < keeps first index (== jnp.argmax(-dist))
  float bestd = 3.4e38f; int bk = 0;
  #pragma unroll 4
  for (int k = 0; k < NK; ++k) {
    const float4 a0 = *(const float4*)&cn[k*DC];
    const float4 a1 = *(const float4*)&cn[k*DC+4];
    float dacc = en[0]*a0.x;
    dacc = fmaf(en[1], a0.y, dacc);
    dacc = fmaf(en[2], a0.z, dacc);
    dacc = fmaf(en[3], a0.w, dacc);
    dacc = fmaf(en[4], a1.x, dacc);
    dacc = fmaf(en[5], a1.y, dacc);
    dacc = fmaf(en[6], a1.z, dacc);
    dacc = fmaf(en[7], a1.w, dacc);
    const float dist = (en2 - 2.0f*dacc) + cn2[k];
    if (dist < bestd) { bestd = dist; bk = k; }
  }
  dout[OFF_IDX + (size_t)b*TT + t] = (float)bk;   // harness reads d_out as f32

  // gather unnormalized code
  float q[DC];
  {
    const float4 q0 = *(const float4*)&cbk[bk*DC];
    const float4 q1 = *(const float4*)&cbk[bk*DC+4];
    q[0]=q0.x; q[1]=q0.y; q[2]=q0.z; q[3]=q0.w;
    q[4]=q1.x; q[5]=q1.y; q[6]=q1.z; q[7]=q1.w;
  }
  // losses: commitment == codebook numerically
  float cl = 0.f;
  #pragma unroll
  for (int i = 0; i < DC; ++i) { const float d = e[i]-q[i]; cl = fmaf(d, d, cl); }

  // rotation trick
  float sq = 0.f;
  #pragma unroll
  for (int i = 0; i < DC; ++i) sq = fmaf(q[i], q[i], sq);
  const float nq = sqrtf(sq);
  const float denq = fmaxf(nq, 1e-12f);
  float qn[DC], rr[DC];
  float sr = 0.f;
  #pragma unroll
  for (int i = 0; i < DC; ++i) { qn[i] = q[i]/denq; rr[i] = en[i]+qn[i]; sr = fmaf(rr[i], rr[i], sr); }
  const float denr = fmaxf(sqrtf(sr), 1e-12f);
  float r_[DC];
  float rdz = 0.f, edz = 0.f;
  #pragma unroll
  for (int i = 0; i < DC; ++i) { r_[i] = rr[i]/denr; rdz = fmaf(r_[i], e[i], rdz); edz = fmaf(en[i], e[i], edz); }
  const float scal = nq / fmaxf(ne, 1e-8f);
  #pragma unroll
  for (int i = 0; i < DC; ++i) {
    const float v = scal * ((e[i] - 2.0f*r_[i]*rdz) + 2.0f*qn[i]*edz);
    zq[((size_t)b*DC + i)*TT + t] = v;
  }

  // block loss reduction -> partial per (b, t-tile)
  lred[tid] = cl;
  __syncthreads();
  for (int s = 128; s > 0; s >>= 1) {
    if (tid < s) lred[tid] += lred[tid + s];
    __syncthreads();
  }
  if (tid == 0) lpart[b*NTT + tt] = lred[0];
}

// ---------------- K3: out_proj (o-split x8) ----------------
__global__ __launch_bounds__(256) void vq_k3_outproj(const float* __restrict__ zq,
    const float* __restrict__ out_w, const float* __restrict__ out_b,
    float* __restrict__ dout)
{
  __shared__ float wo[OCH*DC];
  __shared__ float ob[OCH];
  const int tid = threadIdx.x;
  const int tt = blockIdx.x, b = blockIdx.y, oc = blockIdx.z;
  const int obase = oc*OCH;
  for (int i = tid; i < OCH*DC; i += 256) wo[i] = out_w[obase*DC + i];
  if (tid < OCH) ob[tid] = out_b[obase + tid];
  __syncthreads();
  const int t = tt*TILE + tid;
  float zr[DC];
  #pragma unroll
  for (int c = 0; c < DC; ++c) zr[c] = zq[((size_t)b*DC + c)*TT + t];
  float* op = dout + ((size_t)b*DIN + obase)*TT + t;
  #pragma unroll 4
  for (int o = 0; o < OCH; ++o) {
    const float4 w0 = *(const float4*)&wo[o*DC];
    const float4 w1 = *(const float4*)&wo[o*DC+4];
    float s = ob[o];
    s = fmaf(zr[0], w0.x, s);
    s = fmaf(zr[1], w0.y, s);
    s = fmaf(zr[2], w0.z, s);
    s = fmaf(zr[3], w0.w, s);
    s = fmaf(zr[4], w1.x, s);
    s = fmaf(zr[5], w1.y, s);
    s = fmaf(zr[6], w1.z, s);
    s = fmaf(zr[7], w1.w, s);
    op[(size_t)o*TT] = s;
  }
}

// ---------------- K4: loss finalize ----------------
__global__ void vq_k4_loss(const float* __restrict__ lpart, float* __restrict__ dout)
{
  const int b = threadIdx.x;
  if (b < NB) {
    float s = 0.f;
    for (int j = 0; j < NTT; ++j) s += lpart[b*NTT + j];
    const float v = s / (float)(TT*DC);
    dout[OFF_CL + b] = v;
    dout[OFF_CB + b] = v;
  }
}

extern "C" void kernel_launch(void* const* d_in, const int* in_sizes, int n_in,
                              void* d_out, int out_size, void* d_ws, size_t ws_size,
                              hipStream_t stream) {
  const float* z     = (const float*)d_in[0];
  const float* in_w  = (const float*)d_in[1];
  const float* in_b  = (const float*)d_in[2];
  const float* out_w = (const float*)d_in[3];
  const float* out_b = (const float*)d_in[4];
  const float* cbk   = (const float*)d_in[5];
  float* out = (float*)d_out;
  float* ws  = (float*)d_ws;

  float* P  = ws;                                   // NDC*NB*DC*TT = 2,097,152 f
  float* ZQ = ws + (size_t)NDC*NB*DC*TT;            // NB*DC*TT = 524,288 f
  float* LP = ZQ + (size_t)NB*DC*TT;                // NB*NTT = 256 f

  vq_k1_inproj <<<dim3(NTT, NB, NDC), 256, 0, stream>>>(z, in_w, P);
  vq_k2_search <<<dim3(NTT, NB),      256, 0, stream>>>(P, in_b, cbk, out, ZQ, LP);
  vq_k3_outproj<<<dim3(NTT, NB, NOC), 256, 0, stream>>>(ZQ, out_w, out_b, out);
  vq_k4_loss   <<<1, 256, 0, stream>>>(LP, out);
}